// Round 1
// baseline (326.623 us; speedup 1.0000x reference)
//
#include <hip/hip_runtime.h>
#include <stdint.h>
#include <math.h>

// Problem constants (B=16, N=M=4096, D=3)
#define NPTS 4096
#define NB   16
#define NRES (NPTS * 3)          // 12288 residual scalars per (batch, direction)
// 0-indexed order-statistic ranks for jnp.quantile(q=0.15/0.85, linear):
// pos = q*(NRES-1): 0.15*12287 = 1843.05 ; 0.85*12287 = 10443.95
#define RANK_L0 1843
#define RANK_L1 1844
#define RANK_H0 10443
#define RANK_H1 10444

// ---- order-preserving float<->u32 key transform ----
__device__ __forceinline__ uint32_t f2key(float f) {
    uint32_t u = __float_as_uint(f);
    return (u & 0x80000000u) ? ~u : (u | 0x80000000u);
}
__device__ __forceinline__ float key2f(uint32_t k) {
    uint32_t u = (k & 0x80000000u) ? (k ^ 0x80000000u) : ~k;
    return __uint_as_float(u);
}

// ---------------------------------------------------------------------------
// Kernel 1: brute-force NN residuals.
// grid = (16 query-chunks, 2 directions, 16 batches), block = 256.
// Each block stages all 4096 targets into LDS as (-2tx,-2ty,-2tz,|t|^2),
// then each thread scans all targets for its one query point.
// d' = |t|^2 - 2 q.t  (argmin-equivalent to squared distance).
// ---------------------------------------------------------------------------
__global__ __launch_bounds__(256) void nn_kernel(const float* __restrict__ x,
                                                 const float* __restrict__ y,
                                                 float* __restrict__ res) {
    __shared__ float4 tgt[NPTS];             // 64 KB
    const int b = blockIdx.z, dir = blockIdx.y;
    const float* q = (dir == 0 ? x : y) + (size_t)b * NPTS * 3;
    const float* t = (dir == 0 ? y : x) + (size_t)b * NPTS * 3;

    // Stage targets: each thread handles 16 points as 4 groups of 4 points
    // (4 points = 12 floats = 3 aligned float4 loads).
    #pragma unroll
    for (int g = 0; g < 4; ++g) {
        const int p0 = (g * 256 + threadIdx.x) * 4;
        const float4* src = reinterpret_cast<const float4*>(t + (size_t)p0 * 3);
        const float4 A = src[0], B = src[1], C = src[2];
        tgt[p0 + 0] = make_float4(-2.f * A.x, -2.f * A.y, -2.f * A.z,
                                  A.x * A.x + A.y * A.y + A.z * A.z);
        tgt[p0 + 1] = make_float4(-2.f * A.w, -2.f * B.x, -2.f * B.y,
                                  A.w * A.w + B.x * B.x + B.y * B.y);
        tgt[p0 + 2] = make_float4(-2.f * B.z, -2.f * B.w, -2.f * C.x,
                                  B.z * B.z + B.w * B.w + C.x * C.x);
        tgt[p0 + 3] = make_float4(-2.f * C.y, -2.f * C.z, -2.f * C.w,
                                  C.y * C.y + C.z * C.z + C.w * C.w);
    }
    __syncthreads();

    const int qi = blockIdx.x * 256 + threadIdx.x;
    const float qx = q[qi * 3], qy = q[qi * 3 + 1], qz = q[qi * 3 + 2];
    float best = 3.0e38f;
    int bidx = 0;
    #pragma unroll 4
    for (int j = 0; j < NPTS; ++j) {
        const float4 tj = tgt[j];
        const float d = fmaf(qx, tj.x, fmaf(qy, tj.y, fmaf(qz, tj.z, tj.w)));
        if (d < best) { best = d; bidx = j; }   // strict < keeps first index on ties
    }
    const float4 tb = tgt[bidx];
    // recover t exactly: t = -0.5 * (-2t); residual = q - t in one fma rounding
    const size_t base = (size_t)(b * 2 + dir) * NRES + (size_t)qi * 3;
    res[base + 0] = fmaf(0.5f, tb.x, qx);
    res[base + 1] = fmaf(0.5f, tb.y, qy);
    res[base + 2] = fmaf(0.5f, tb.z, qz);
}

// ---------------------------------------------------------------------------
// Kernel 2: robust masked std per (batch, direction). 32 blocks x 256 threads.
// ---------------------------------------------------------------------------
__device__ __forceinline__ double block_sum_d(double v, double* red) {
    #pragma unroll
    for (int off = 32; off; off >>= 1) v += __shfl_down(v, off);
    __syncthreads();
    if ((threadIdx.x & 63) == 0) red[threadIdx.x >> 6] = v;
    __syncthreads();
    return red[0] + red[1] + red[2] + red[3];
}
__device__ __forceinline__ int block_sum_i(int v, int* red) {
    #pragma unroll
    for (int off = 32; off; off >>= 1) v += __shfl_down(v, off);
    __syncthreads();
    if ((threadIdx.x & 63) == 0) red[threadIdx.x >> 6] = v;
    __syncthreads();
    return red[0] + red[1] + red[2] + red[3];
}

__global__ __launch_bounds__(256) void sigma_kernel(const float* __restrict__ res,
                                                    float* __restrict__ sig) {
    __shared__ uint32_t keys[NRES];          // 48 KB
    __shared__ double dred[4];
    __shared__ int    ired[4];
    __shared__ int    icnt[4];

    const int pair = blockIdx.x;
    const int tid = threadIdx.x;
    const float* v = res + (size_t)pair * NRES;

    // Load, key-transform, and accumulate full-array sum/sumsq (for fallback)
    double s = 0.0, s2 = 0.0;
    for (int i = tid; i < NRES; i += 256) {
        const float f = v[i];
        keys[i] = f2key(f);
        s += f;
        s2 += (double)f * (double)f;
    }
    __syncthreads();                          // keys visible to all
    const double S  = block_sum_d(s, dred);
    const double S2 = block_sum_d(s2, dred);
    const double mu = S / NRES;
    double var_all = (S2 - S * mu) / (NRES - 1);
    const double sd = sqrt(var_all > 0.0 ? var_all : 0.0);

    // 4 simultaneous binary searches on u32 key space for exact order stats
    const int ranks[4] = {RANK_L0, RANK_L1, RANK_H0, RANK_H1};
    uint32_t lo4[4] = {0u, 0u, 0u, 0u};
    uint32_t hi4[4] = {0xFFFFFFFFu, 0xFFFFFFFFu, 0xFFFFFFFFu, 0xFFFFFFFFu};
    for (int it = 0; it < 32; ++it) {
        uint32_t mid[4];
        #pragma unroll
        for (int s_ = 0; s_ < 4; ++s_) mid[s_] = lo4[s_] + ((hi4[s_] - lo4[s_]) >> 1);
        if (tid < 4) icnt[tid] = 0;
        __syncthreads();
        int cnt[4] = {0, 0, 0, 0};
        for (int i = tid; i < NRES; i += 256) {
            const uint32_t k = keys[i];
            #pragma unroll
            for (int s_ = 0; s_ < 4; ++s_) cnt[s_] += (k <= mid[s_]) ? 1 : 0;
        }
        #pragma unroll
        for (int s_ = 0; s_ < 4; ++s_) {
            #pragma unroll
            for (int off = 32; off; off >>= 1) cnt[s_] += __shfl_down(cnt[s_], off);
        }
        if ((tid & 63) == 0) {
            #pragma unroll
            for (int s_ = 0; s_ < 4; ++s_) atomicAdd(&icnt[s_], cnt[s_]);
        }
        __syncthreads();
        #pragma unroll
        for (int s_ = 0; s_ < 4; ++s_) {
            if (icnt[s_] >= ranks[s_] + 1) hi4[s_] = mid[s_];
            else                           lo4[s_] = mid[s_] + 1;
        }
        __syncthreads();                      // protect icnt reset next iter
    }

    // Linear-interpolated quantiles (jnp.quantile, method='linear')
    const double vl0 = (double)key2f(lo4[0]), vl1 = (double)key2f(lo4[1]);
    const double vh0 = (double)key2f(lo4[2]), vh1 = (double)key2f(lo4[3]);
    const double fr_lo = 0.15 * (NRES - 1) - (double)RANK_L0;  // ~0.05
    const double fr_hi = 0.85 * (NRES - 1) - (double)RANK_H0;  // ~0.95
    const float q_lo = (float)(vl0 + fr_lo * (vl1 - vl0));
    const float q_hi = (float)(vh0 + fr_hi * (vh1 - vh0));

    // Pass 1: counts + sums under both predicates
    int cq = 0, cs = 0;
    double sq = 0.0, ss = 0.0;
    for (int i = tid; i < NRES; i += 256) {
        const float f = key2f(keys[i]);
        const bool mq = (f < q_lo) || (f > q_hi);
        const bool ms = fabs((double)f - mu) > sd;
        cq += mq; cs += ms;
        if (mq) sq += f;
        if (ms) ss += f;
    }
    const int cq_t = block_sum_i(cq, ired);
    const int cs_t = block_sum_i(cs, ired);
    const double sq_t = block_sum_d(sq, dred);
    const double ss_t = block_sum_d(ss, dred);

    int mode;           // 0 = quantile mask, 1 = simple |x-mu|>sd, 2 = all
    double cnt_sel, sum_sel;
    if (cq_t > 0)      { mode = 0; cnt_sel = cq_t; sum_sel = sq_t; }
    else if (cs_t > 0) { mode = 1; cnt_sel = cs_t; sum_sel = ss_t; }
    else               { mode = 2; cnt_sel = NRES; sum_sel = S; }
    const double mean_w = sum_sel / cnt_sel;

    // Pass 2: masked unbiased variance
    double acc = 0.0;
    for (int i = tid; i < NRES; i += 256) {
        const float f = key2f(keys[i]);
        bool w;
        if (mode == 0)      w = (f < q_lo) || (f > q_hi);
        else if (mode == 1) w = fabs((double)f - mu) > sd;
        else                w = true;
        if (w) { const double d = (double)f - mean_w; acc += d * d; }
    }
    const double var = block_sum_d(acc, dred) / (cnt_sel - 1.0);
    if (tid == 0) sig[pair] = (float)sqrt(var);
}

// ---------------------------------------------------------------------------
// Kernel 3: out = mean_b max(sig[2b], sig[2b+1])
// ---------------------------------------------------------------------------
__global__ void final_kernel(const float* __restrict__ sig, float* __restrict__ out) {
    const int lane = threadIdx.x;
    float m = 0.f;
    if (lane < NB) m = fmaxf(sig[2 * lane], sig[2 * lane + 1]);
    #pragma unroll
    for (int off = 8; off; off >>= 1) m += __shfl_down(m, off);
    if (lane == 0) out[0] = m / (float)NB;
}

extern "C" void kernel_launch(void* const* d_in, const int* in_sizes, int n_in,
                              void* d_out, int out_size, void* d_ws, size_t ws_size,
                              hipStream_t stream) {
    const float* x = (const float*)d_in[0];
    const float* y = (const float*)d_in[1];
    float* res = (float*)d_ws;                       // 32 * 12288 floats = 1.5 MB
    float* sig = res + 32 * NRES;                    // 32 floats
    dim3 g1(NPTS / 256, 2, NB);                      // (16, 2, 16) = 512 blocks
    nn_kernel<<<g1, 256, 0, stream>>>(x, y, res);
    sigma_kernel<<<32, 256, 0, stream>>>(res, sig);
    final_kernel<<<1, 64, 0, stream>>>(sig, (float*)d_out);
}

// Round 2
// 198.459 us; speedup vs baseline: 1.6458x; 1.6458x over previous
//
#include <hip/hip_runtime.h>
#include <stdint.h>
#include <math.h>

// Problem constants (B=16, N=M=4096, D=3)
#define NPTS  4096
#define NB    16
#define NRES  (NPTS * 3)          // 12288 residuals per (batch, direction)
#define NPAIR 32                  // 16 batches x 2 directions
#define NQTOT (NPAIR * NPTS)      // 131072 queries total
#define TCH   512                 // targets per chunk (8 KB LDS)
#define NTCH  (NPTS / TCH)        // 8 chunks
#define QPT   8                   // queries per thread in nn
// 0-indexed order-statistic ranks for jnp.quantile(0.15/0.85, linear):
#define RANK_L0 1843
#define RANK_L1 1844
#define RANK_H0 10443
#define RANK_H1 10444

// ---- order-preserving float<->u32 key transform ----
__device__ __forceinline__ uint32_t f2key(float f) {
    uint32_t u = __float_as_uint(f);
    return (u & 0x80000000u) ? ~u : (u | 0x80000000u);
}
__device__ __forceinline__ float key2f(uint32_t k) {
    uint32_t u = (k & 0x80000000u) ? (k ^ 0x80000000u) : ~k;
    return __uint_as_float(u);
}

// ---------------------------------------------------------------------------
// Kernel 1: brute-force NN, chunked. grid=(2 qchunks, 8 tchunks, 32 pairdirs).
// Each thread owns 8 queries; each LDS target read is amortized 8x.
// Cross-chunk reduction via atomicMin on packed (key(d)<<32 | global_idx):
// equal d -> smaller idx wins = first-argmin, matching the reference.
// ---------------------------------------------------------------------------
__global__ __launch_bounds__(256) void nn_kernel(const float* __restrict__ x,
                                                 const float* __restrict__ y,
                                                 unsigned long long* __restrict__ part) {
    __shared__ float4 tgt[TCH];              // 8 KB
    const int pd = blockIdx.z, b = pd >> 1, dir = pd & 1;
    const int tchunk = blockIdx.y;
    const float* q = (dir == 0 ? x : y) + (size_t)b * NPTS * 3;
    const float* t = (dir == 0 ? y : x) + (size_t)b * NPTS * 3;
    const int tid = threadIdx.x;

    // Stage this chunk's 512 targets as (-2tx,-2ty,-2tz,|t|^2).
    if (tid < TCH / 4) {
        const int p0 = tid * 4;
        const float4* src = reinterpret_cast<const float4*>(t + ((size_t)tchunk * TCH + p0) * 3);
        const float4 A = src[0], B = src[1], C = src[2];
        tgt[p0 + 0] = make_float4(-2.f * A.x, -2.f * A.y, -2.f * A.z,
                                  A.x * A.x + A.y * A.y + A.z * A.z);
        tgt[p0 + 1] = make_float4(-2.f * A.w, -2.f * B.x, -2.f * B.y,
                                  A.w * A.w + B.x * B.x + B.y * B.y);
        tgt[p0 + 2] = make_float4(-2.f * B.z, -2.f * B.w, -2.f * C.x,
                                  B.z * B.z + B.w * B.w + C.x * C.x);
        tgt[p0 + 3] = make_float4(-2.f * C.y, -2.f * C.z, -2.f * C.w,
                                  C.y * C.y + C.z * C.z + C.w * C.w);
    }
    __syncthreads();

    // Load this thread's 8 query points (24 floats = 6 aligned float4).
    const int qbase = blockIdx.x * (256 * QPT) + tid * QPT;
    const float4* qp = reinterpret_cast<const float4*>(q + (size_t)qbase * 3);
    const float4 v0 = qp[0], v1 = qp[1], v2 = qp[2], v3 = qp[3], v4 = qp[4], v5 = qp[5];
    const float qx[8] = {v0.x, v0.w, v1.z, v2.y, v3.x, v3.w, v4.z, v5.y};
    const float qy[8] = {v0.y, v1.x, v1.w, v2.z, v3.y, v4.x, v4.w, v5.z};
    const float qz[8] = {v0.z, v1.y, v2.x, v2.w, v3.z, v4.y, v5.x, v5.w};
    float best[8];
    int bj[8];
    #pragma unroll
    for (int k = 0; k < 8; ++k) { best[k] = 3.0e38f; bj[k] = 0; }

    #pragma unroll 2
    for (int j = 0; j < TCH; ++j) {
        const float4 tj = tgt[j];
        #pragma unroll
        for (int k = 0; k < 8; ++k) {
            const float d = fmaf(qx[k], tj.x, fmaf(qy[k], tj.y, fmaf(qz[k], tj.z, tj.w)));
            if (d < best[k]) { best[k] = d; bj[k] = j; }   // strict < = first index
        }
    }

    const int gbase = tchunk * TCH;
    #pragma unroll
    for (int k = 0; k < 8; ++k) {
        const unsigned long long pk =
            ((unsigned long long)f2key(best[k]) << 32) | (unsigned int)(gbase + bj[k]);
        atomicMin(&part[(size_t)pd * NPTS + qbase + k], pk);
    }
}

// ---------------------------------------------------------------------------
// Kernel 2: robust masked std per pair. 32 blocks x 1024 threads.
// Residuals recomputed inline from part[]; exact order stats via 3-level
// radix selection (11/11/10 bits) with LDS histograms + block prefix scan.
// ---------------------------------------------------------------------------
#define STH 1024

__device__ __forceinline__ void scan2049(uint32_t* hc, uint32_t* wtmp) {
    // In-place exclusive prefix over hc[0..2047]; hc[2048] = total.
    const int tid = threadIdx.x, lane = tid & 63, wv = tid >> 6;
    const uint32_t a = hc[2 * tid], bb = hc[2 * tid + 1];
    const uint32_t v = a + bb;
    uint32_t sc = v;                          // inclusive scan over threads
    #pragma unroll
    for (int off = 1; off < 64; off <<= 1) {
        const uint32_t u = __shfl(sc, lane - off);
        if (lane >= off) sc += u;
    }
    if (lane == 63) wtmp[wv] = sc;
    __syncthreads();
    uint32_t wbase = 0;
    #pragma unroll
    for (int k = 0; k < 16; ++k) wbase += (k < wv) ? wtmp[k] : 0u;
    const uint32_t ex = wbase + sc - v;       // exclusive prefix for bin 2*tid
    hc[2 * tid] = ex;
    hc[2 * tid + 1] = ex + a;
    if (tid == 1023) hc[2048] = ex + a + bb;
    __syncthreads();
}

__device__ __forceinline__ int ub2048(const uint32_t* cum, uint32_t r) {
    int lo = 0, hi = 2047;                    // largest b with cum[b] <= r
    while (lo < hi) {
        const int mid = (lo + hi + 1) >> 1;
        if (cum[mid] <= r) lo = mid; else hi = mid - 1;
    }
    return lo;
}

__global__ __launch_bounds__(1024) void sigma_kernel(const float* __restrict__ x,
                                                     const float* __restrict__ y,
                                                     const unsigned long long* __restrict__ part,
                                                     float* __restrict__ sig) {
    __shared__ uint32_t keys[NRES];           // 48 KB
    __shared__ uint32_t hcum[2049];           // histogram, scanned in place
    __shared__ uint32_t wtmp[16];
    __shared__ double dred[32];
    __shared__ int ired[32];
    __shared__ uint32_t pfx1[4], pfx2[4], rnk1[4], rnk2[4], selkey[4];

    const int pair = blockIdx.x, b = pair >> 1, dir = pair & 1;
    const int tid = threadIdx.x, lane = tid & 63, wv = tid >> 6;
    const float* q = (dir == 0 ? x : y) + (size_t)b * NPTS * 3;
    const float* t = (dir == 0 ? y : x) + (size_t)b * NPTS * 3;

    // Pass A: residuals from argmin, keys into LDS, full sum/sumsq (fallback)
    double s = 0.0, s2 = 0.0;
    for (int qi = tid; qi < NPTS; qi += STH) {
        const unsigned int idx = (unsigned int)(part[(size_t)pair * NPTS + qi] & 0xFFFFFFFFull);
        const float rx = q[qi * 3 + 0] - t[idx * 3 + 0];
        const float ry = q[qi * 3 + 1] - t[idx * 3 + 1];
        const float rz = q[qi * 3 + 2] - t[idx * 3 + 2];
        keys[qi * 3 + 0] = f2key(rx);
        keys[qi * 3 + 1] = f2key(ry);
        keys[qi * 3 + 2] = f2key(rz);
        s += (double)rx + (double)ry + (double)rz;
        s2 += (double)rx * rx + (double)ry * ry + (double)rz * rz;
    }
    {
        double a = s, c = s2;
        #pragma unroll
        for (int off = 32; off; off >>= 1) { a += __shfl_down(a, off); c += __shfl_down(c, off); }
        if (lane == 0) { dred[wv] = a; dred[16 + wv] = c; }
    }
    __syncthreads();
    double S = 0.0, S2 = 0.0;
    for (int k = 0; k < 16; ++k) { S += dred[k]; S2 += dred[16 + k]; }
    __syncthreads();
    const double mu = S / NRES;
    const double var_all = (S2 - S * mu) / (NRES - 1);
    const double sd = sqrt(var_all > 0.0 ? var_all : 0.0);

    // ---- 3-level radix selection for ranks {1843,1844,10443,10444} ----
    const uint32_t ranks[4] = {RANK_L0, RANK_L1, RANK_H0, RANK_H1};
    // Level 1: top 11 bits
    hcum[tid] = 0; hcum[tid + 1024] = 0; if (tid == 0) hcum[2048] = 0;
    __syncthreads();
    for (int e = tid; e < NRES; e += STH) atomicAdd(&hcum[keys[e] >> 21], 1u);
    __syncthreads();
    scan2049(hcum, wtmp);
    if (tid < 4) {
        const uint32_t r = ranks[tid];
        const int bb = ub2048(hcum, r);
        pfx1[tid] = (uint32_t)bb;
        rnk1[tid] = r - hcum[bb];
    }
    __syncthreads();
    // Level 2: bits 20:10 within prefix (dedupe adjacent identical prefixes)
    for (int i = 0; i < 4; ++i) {
        const uint32_t p = pfx1[i];
        const bool np = (i == 0) || (p != pfx1[i - 1]);
        if (np) {
            hcum[tid] = 0; hcum[tid + 1024] = 0;
            __syncthreads();
            for (int e = tid; e < NRES; e += STH) {
                const uint32_t k = keys[e];
                if ((k >> 21) == p) atomicAdd(&hcum[(k >> 10) & 0x7FFu], 1u);
            }
            __syncthreads();
            scan2049(hcum, wtmp);
        }
        if (tid == 0) {
            const int bb = ub2048(hcum, rnk1[i]);
            pfx2[i] = (p << 11) | (uint32_t)bb;
            rnk2[i] = rnk1[i] - hcum[bb];
        }
        __syncthreads();
    }
    // Level 3: bits 9:0 within 22-bit prefix -> exact key
    for (int i = 0; i < 4; ++i) {
        const uint32_t p = pfx2[i];
        const bool np = (i == 0) || (p != pfx2[i - 1]);
        if (np) {
            hcum[tid] = 0; hcum[tid + 1024] = 0;
            __syncthreads();
            for (int e = tid; e < NRES; e += STH) {
                const uint32_t k = keys[e];
                if ((k >> 10) == p) atomicAdd(&hcum[k & 0x3FFu], 1u);
            }
            __syncthreads();
            scan2049(hcum, wtmp);
        }
        if (tid == 0) {
            const int bb = ub2048(hcum, rnk2[i]);
            selkey[i] = (p << 10) | (uint32_t)bb;
        }
        __syncthreads();
    }

    // Linear-interpolated quantiles (jnp.quantile, method='linear')
    const double vl0 = (double)key2f(selkey[0]), vl1 = (double)key2f(selkey[1]);
    const double vh0 = (double)key2f(selkey[2]), vh1 = (double)key2f(selkey[3]);
    const double fr_lo = 0.15 * (NRES - 1) - (double)RANK_L0;   // ~0.05
    const double fr_hi = 0.85 * (NRES - 1) - (double)RANK_H0;   // ~0.95
    const float q_lo = (float)(vl0 + fr_lo * (vl1 - vl0));
    const float q_hi = (float)(vh0 + fr_hi * (vh1 - vh0));

    // Pass B: counts + sums under both predicates
    int cq = 0, cs = 0;
    double sq = 0.0, ss = 0.0;
    for (int e = tid; e < NRES; e += STH) {
        const float f = key2f(keys[e]);
        const bool mq = (f < q_lo) || (f > q_hi);
        const bool ms = fabs((double)f - mu) > sd;
        cq += mq; cs += ms;
        if (mq) sq += f;
        if (ms) ss += f;
    }
    {
        double a = sq, c = ss;
        int ai = cq, ci = cs;
        #pragma unroll
        for (int off = 32; off; off >>= 1) {
            a += __shfl_down(a, off); c += __shfl_down(c, off);
            ai += __shfl_down(ai, off); ci += __shfl_down(ci, off);
        }
        if (lane == 0) { dred[wv] = a; dred[16 + wv] = c; ired[wv] = ai; ired[16 + wv] = ci; }
    }
    __syncthreads();
    double sq_t = 0.0, ss_t = 0.0;
    int cq_t = 0, cs_t = 0;
    for (int k = 0; k < 16; ++k) {
        sq_t += dred[k]; ss_t += dred[16 + k];
        cq_t += ired[k]; cs_t += ired[16 + k];
    }
    __syncthreads();

    int mode;            // 0 = quantile mask, 1 = simple |x-mu|>sd, 2 = all
    double cnt_sel, sum_sel;
    if (cq_t > 0)      { mode = 0; cnt_sel = cq_t; sum_sel = sq_t; }
    else if (cs_t > 0) { mode = 1; cnt_sel = cs_t; sum_sel = ss_t; }
    else               { mode = 2; cnt_sel = NRES; sum_sel = S; }
    const double mean_w = sum_sel / cnt_sel;

    // Pass C: masked unbiased variance
    double acc = 0.0;
    for (int e = tid; e < NRES; e += STH) {
        const float f = key2f(keys[e]);
        bool w;
        if (mode == 0)      w = (f < q_lo) || (f > q_hi);
        else if (mode == 1) w = fabs((double)f - mu) > sd;
        else                w = true;
        if (w) { const double d = (double)f - mean_w; acc += d * d; }
    }
    {
        double a = acc;
        #pragma unroll
        for (int off = 32; off; off >>= 1) a += __shfl_down(a, off);
        if (lane == 0) dred[wv] = a;
    }
    __syncthreads();
    double acc_t = 0.0;
    for (int k = 0; k < 16; ++k) acc_t += dred[k];
    if (tid == 0) sig[pair] = (float)sqrt(acc_t / (cnt_sel - 1.0));
}

// ---------------------------------------------------------------------------
// Kernel 3: out = mean_b max(sig[2b], sig[2b+1])
// ---------------------------------------------------------------------------
__global__ void final_kernel(const float* __restrict__ sig, float* __restrict__ out) {
    const int lane = threadIdx.x;
    float m = 0.f;
    if (lane < NB) m = fmaxf(sig[2 * lane], sig[2 * lane + 1]);
    #pragma unroll
    for (int off = 8; off; off >>= 1) m += __shfl_down(m, off);
    if (lane == 0) out[0] = m / (float)NB;
}

extern "C" void kernel_launch(void* const* d_in, const int* in_sizes, int n_in,
                              void* d_out, int out_size, void* d_ws, size_t ws_size,
                              hipStream_t stream) {
    const float* x = (const float*)d_in[0];
    const float* y = (const float*)d_in[1];
    unsigned long long* part = (unsigned long long*)d_ws;          // 1 MB
    float* sig = (float*)((char*)d_ws + (size_t)NQTOT * 8);        // 32 floats
    hipMemsetAsync(d_ws, 0xFF, (size_t)NQTOT * 8, stream);         // part = +inf
    dim3 g1(NPTS / (256 * QPT), NTCH, NPAIR);                      // (2, 8, 32)
    nn_kernel<<<g1, 256, 0, stream>>>(x, y, part);
    sigma_kernel<<<NPAIR, STH, 0, stream>>>(x, y, part, sig);
    final_kernel<<<1, 64, 0, stream>>>(sig, (float*)d_out);
}

// Round 3
// 137.072 us; speedup vs baseline: 2.3829x; 1.4478x over previous
//
#include <hip/hip_runtime.h>
#include <stdint.h>
#include <math.h>

typedef float f32x2 __attribute__((ext_vector_type(2)));
typedef float f32x4 __attribute__((ext_vector_type(4)));
typedef unsigned long long ull;

// Problem constants (B=16, N=M=4096, D=3)
#define NPTS  4096
#define NB    16
#define NRES  12288               // residuals per (batch, direction)
#define NPAIR 32                  // 16 batches x 2 directions
#define TCH   512                 // targets per chunk (8 KB LDS)
#define NTCH  8
#define QPT   4                   // queries per thread in nn
// 0-indexed order-statistic ranks for jnp.quantile(0.15/0.85, linear)
#define RANK_LO 1843u
#define RANK_HI 10443u

__device__ __forceinline__ uint32_t f2key(float f) {
    uint32_t u = __float_as_uint(f);
    return (u & 0x80000000u) ? ~u : (u | 0x80000000u);
}
__device__ __forceinline__ float key2f(uint32_t k) {
    uint32_t u = (k & 0x80000000u) ? (k ^ 0x80000000u) : ~k;
    return __uint_as_float(u);
}
__device__ __forceinline__ f32x2 fma2(f32x2 a, f32x2 b, f32x2 c) {
    return __builtin_elementwise_fma(a, b, c);   // -> v_pk_fma_f32
}

// ---------------------------------------------------------------------------
// Kernel 1: brute-force NN. grid=(4 qchunks, 8 tchunks, 32 pairdirs), 256 thr.
// LDS pair-interleaved targets; packed fp32 FMA; group-min(16) + deferred
// index resolution; plain coalesced candidate stores (no atomics).
// ---------------------------------------------------------------------------
__global__ __launch_bounds__(256, 4) void nn_kernel(const float* __restrict__ x,
                                                    const float* __restrict__ y,
                                                    ull* __restrict__ part) {
    __shared__ f32x4 tgt[TCH / 2][2];   // [p][0]={-2x0,-2x1,-2y0,-2y1} [1]={-2z0,-2z1,w0,w1}
    const int pd = blockIdx.z, b = pd >> 1, dir = pd & 1;
    const int tchunk = blockIdx.y;
    const float* q = (dir == 0 ? x : y) + (size_t)b * NPTS * 3;
    const float* t = (dir == 0 ? y : x) + (size_t)b * NPTS * 3;
    const int tid = threadIdx.x;

    {   // stage: thread p preps target pair (2p, 2p+1): floats {x0,y0,z0,x1,y1,z1}
        const float2* src = reinterpret_cast<const float2*>(t + ((size_t)tchunk * TCH + tid * 2) * 3);
        const float2 a = src[0], c = src[1], e = src[2];   // {x0,y0},{z0,x1},{y1,z1}
        const float w0 = fmaf(c.x, c.x, fmaf(a.y, a.y, a.x * a.x));
        const float w1 = fmaf(e.y, e.y, fmaf(e.x, e.x, c.y * c.y));
        tgt[tid][0] = (f32x4){-2.f * a.x, -2.f * c.y, -2.f * a.y, -2.f * e.x};
        tgt[tid][1] = (f32x4){-2.f * c.x, -2.f * e.y, w0, w1};
    }
    __syncthreads();

    // 4 strided queries per thread (stride 256 -> coalesced candidate stores)
    f32x2 qx2[QPT], qy2[QPT], qz2[QPT];
    #pragma unroll
    for (int k = 0; k < QPT; ++k) {
        const float* qp = q + (size_t)(blockIdx.x * 1024 + k * 256 + tid) * 3;
        const float a = qp[0], bb = qp[1], c = qp[2];
        qx2[k] = (f32x2){a, a};
        qy2[k] = (f32x2){bb, bb};
        qz2[k] = (f32x2){c, c};
    }

    float best[QPT];
    int gi[QPT];
    #pragma unroll
    for (int k = 0; k < QPT; ++k) { best[k] = 3.0e38f; gi[k] = 0; }

    for (int g = 0; g < TCH / 16; ++g) {          // 32 groups of 16 targets
        f32x2 gm[QPT];
        #pragma unroll
        for (int k = 0; k < QPT; ++k) gm[k] = (f32x2){3.0e38f, 3.0e38f};
        #pragma unroll
        for (int jj = 0; jj < 8; ++jj) {
            const f32x4 A = tgt[g * 8 + jj][0];
            const f32x4 B = tgt[g * 8 + jj][1];
            const f32x2 tx = __builtin_shufflevector(A, A, 0, 1);
            const f32x2 ty = __builtin_shufflevector(A, A, 2, 3);
            const f32x2 tz = __builtin_shufflevector(B, B, 0, 1);
            const f32x2 w2 = __builtin_shufflevector(B, B, 2, 3);
            #pragma unroll
            for (int k = 0; k < QPT; ++k) {
                const f32x2 d = fma2(qx2[k], tx, fma2(qy2[k], ty, fma2(qz2[k], tz, w2)));
                gm[k] = __builtin_elementwise_min(gm[k], d);
            }
        }
        #pragma unroll
        for (int k = 0; k < QPT; ++k) {
            const float m = fminf(gm[k].x, gm[k].y);
            if (m < best[k]) { best[k] = m; gi[k] = g; }   // strict < = earliest group
        }
    }

    // Resolve exact first-index within the winning group (identical fma chain)
    #pragma unroll
    for (int k = 0; k < QPT; ++k) {
        const float bk = best[k];
        int sel = 15;
        #pragma unroll
        for (int jj = 7; jj >= 0; --jj) {          // reverse: last assign = lowest j
            const f32x4 A = tgt[gi[k] * 8 + jj][0];
            const f32x4 B = tgt[gi[k] * 8 + jj][1];
            const f32x2 tx = __builtin_shufflevector(A, A, 0, 1);
            const f32x2 ty = __builtin_shufflevector(A, A, 2, 3);
            const f32x2 tz = __builtin_shufflevector(B, B, 0, 1);
            const f32x2 w2 = __builtin_shufflevector(B, B, 2, 3);
            const f32x2 d = fma2(qx2[k], tx, fma2(qy2[k], ty, fma2(qz2[k], tz, w2)));
            if (d.y == bk) sel = jj * 2 + 1;
            if (d.x == bk) sel = jj * 2;
        }
        const uint32_t gidx = (uint32_t)(tchunk * TCH + gi[k] * 16 + sel);
        const ull pk = ((ull)f2key(bk) << 32) | gidx;
        part[((size_t)(pd * NTCH + tchunk)) * NPTS + blockIdx.x * 1024 + k * 256 + tid] = pk;
    }
}

// ---------------------------------------------------------------------------
// Kernel 2: robust masked std. 32 blocks x 512 threads; keys in registers
// (24/thread); 3-level radix selection with 2 concurrent histograms.
// ---------------------------------------------------------------------------
#define STH 512

__device__ __forceinline__ void scan2048(uint32_t* h, uint32_t* wtmp) {
    // exclusive prefix over h[0..2047]; each thread owns 4 bins; 512 threads
    const int tid = threadIdx.x, lane = tid & 63, wv = tid >> 6;
    const int i = tid * 4;
    const uint32_t a0 = h[i], a1 = h[i + 1], a2 = h[i + 2], a3 = h[i + 3];
    const uint32_t v = a0 + a1 + a2 + a3;
    uint32_t sc = v;
    #pragma unroll
    for (int off = 1; off < 64; off <<= 1) {
        const uint32_t u = __shfl_up(sc, off);
        if (lane >= off) sc += u;
    }
    if (lane == 63) wtmp[wv] = sc;
    __syncthreads();
    uint32_t base = 0;
    #pragma unroll
    for (int k = 0; k < 8; ++k) base += (k < wv) ? wtmp[k] : 0u;
    const uint32_t ex = base + sc - v;
    h[i] = ex; h[i + 1] = ex + a0; h[i + 2] = ex + a0 + a1; h[i + 3] = ex + a0 + a1 + a2;
    __syncthreads();
}

__device__ __forceinline__ int ubin(const uint32_t* cum, int n, uint32_t r) {
    int lo = 0, hi = n - 1;                       // largest b with cum[b] <= r
    while (lo < hi) {
        const int mid = (lo + hi + 1) >> 1;
        if (cum[mid] <= r) lo = mid; else hi = mid - 1;
    }
    return lo;
}

__global__ __launch_bounds__(512) void sigma_kernel(const float* __restrict__ x,
                                                    const float* __restrict__ y,
                                                    const ull* __restrict__ part,
                                                    float* __restrict__ sig) {
    __shared__ uint32_t hist[4096];               // 16 KB
    __shared__ uint32_t wtmp[8];
    __shared__ double dred[16];
    __shared__ int ired[16];
    __shared__ uint32_t umin[16];
    __shared__ uint32_t bc[8];

    const int pair = blockIdx.x, b = pair >> 1, dir = pair & 1;
    const int tid = threadIdx.x, lane = tid & 63, wv = tid >> 6;
    const float* q = (dir == 0 ? x : y) + (size_t)b * NPTS * 3;
    const float* t = (dir == 0 ? y : x) + (size_t)b * NPTS * 3;

    // Pass A: min over 8 chunk candidates, residuals -> register keys
    uint32_t key[24];
    double s = 0.0, s2 = 0.0;
    #pragma unroll
    for (int kq = 0; kq < 8; ++kq) {
        const int qi = kq * STH + tid;
        ull mk = ~0ull;
        #pragma unroll
        for (int c = 0; c < NTCH; ++c) {
            const ull v = part[((size_t)(pair * NTCH + c)) * NPTS + qi];
            mk = (v < mk) ? v : mk;               // ties -> smaller global idx
        }
        const uint32_t idx = (uint32_t)mk;
        const float rx = q[qi * 3 + 0] - t[idx * 3 + 0];
        const float ry = q[qi * 3 + 1] - t[idx * 3 + 1];
        const float rz = q[qi * 3 + 2] - t[idx * 3 + 2];
        key[kq * 3 + 0] = f2key(rx);
        key[kq * 3 + 1] = f2key(ry);
        key[kq * 3 + 2] = f2key(rz);
        s += (double)rx + (double)ry + (double)rz;
        s2 += (double)rx * rx + (double)ry * ry + (double)rz * rz;
    }
    {
        double a = s, c2 = s2;
        #pragma unroll
        for (int off = 32; off; off >>= 1) { a += __shfl_down(a, off); c2 += __shfl_down(c2, off); }
        if (lane == 0) { dred[wv] = a; dred[8 + wv] = c2; }
    }
    __syncthreads();
    double S = 0.0, S2 = 0.0;
    for (int k = 0; k < 8; ++k) { S += dred[k]; S2 += dred[8 + k]; }
    const double mu = S / NRES;
    const double var_all = (S2 - S * mu) / (NRES - 1);
    const double sd = sqrt(var_all > 0.0 ? var_all : 0.0);

    // ---- Level 1: 11-bit histogram ----
    #pragma unroll
    for (int j = 0; j < 8; ++j) hist[tid * 8 + j] = 0u;
    __syncthreads();
    #pragma unroll
    for (int e = 0; e < 24; ++e) atomicAdd(&hist[key[e] >> 21], 1u);
    __syncthreads();
    scan2048(hist, wtmp);
    if (tid < 2) {
        const uint32_t r = tid ? RANK_HI : RANK_LO;
        const int bb = ubin(hist, 2048, r);
        bc[tid * 4 + 0] = (uint32_t)bb;           // 11-bit prefix
        bc[tid * 4 + 1] = r - hist[bb];           // residual rank
    }
    __syncthreads();

    // ---- Level 2: two concurrent 11-bit histograms ----
    const uint32_t pA1 = bc[0], rA1 = bc[1], pB1 = bc[4], rB1 = bc[5];
    #pragma unroll
    for (int j = 0; j < 8; ++j) hist[tid * 8 + j] = 0u;
    __syncthreads();
    #pragma unroll
    for (int e = 0; e < 24; ++e) {
        const uint32_t k = key[e];
        const uint32_t p = k >> 21, bin = (k >> 10) & 2047u;
        if (p == pA1) atomicAdd(&hist[bin], 1u);
        if (p == pB1) atomicAdd(&hist[2048 + bin], 1u);
    }
    __syncthreads();
    scan2048(hist, wtmp);
    scan2048(hist + 2048, wtmp);
    if (tid < 2) {
        const uint32_t* h = hist + tid * 2048;
        const uint32_t p = tid ? pB1 : pA1;
        const uint32_t r = tid ? rB1 : rA1;
        const int bb = ubin(h, 2048, r);
        bc[tid * 4 + 0] = (p << 11) | (uint32_t)bb;   // 22-bit prefix
        bc[tid * 4 + 1] = r - h[bb];
    }
    __syncthreads();

    // ---- Level 3: two concurrent 10-bit histograms -> exact keys ----
    const uint32_t pA2 = bc[0], rA2 = bc[1], pB2 = bc[4], rB2 = bc[5];
    #pragma unroll
    for (int j = 0; j < 8; ++j) hist[tid * 8 + j] = 0u;
    __syncthreads();
    #pragma unroll
    for (int e = 0; e < 24; ++e) {
        const uint32_t k = key[e];
        if ((k >> 10) == pA2) atomicAdd(&hist[k & 1023u], 1u);
        if ((k >> 10) == pB2) atomicAdd(&hist[2048 + (k & 1023u)], 1u);
    }
    __syncthreads();
    scan2048(hist, wtmp);
    scan2048(hist + 2048, wtmp);
    if (tid < 2) {
        const uint32_t* h = hist + tid * 2048;
        const uint32_t p = tid ? pB2 : pA2;
        const uint32_t r = tid ? rB2 : rA2;
        const uint32_t rtot = tid ? RANK_HI : RANK_LO;
        const int bb = ubin(h, 1024, r);
        const uint32_t k0 = (p << 10) | (uint32_t)bb;
        const uint32_t abs_le = (rtot - r) + h[bb + 1];   // elems <= k0 overall
        bc[tid * 4 + 0] = k0;
        bc[tid * 4 + 1] = (abs_le >= rtot + 2u) ? 1u : 0u; // rank+1 shares key?
    }
    __syncthreads();

    // ---- rank+1 keys: duplicate-covered or min key strictly greater ----
    const uint32_t k0 = bc[0], dup1 = bc[1], k2 = bc[4], dup3 = bc[5];
    uint32_t m1 = 0xFFFFFFFFu, m3 = 0xFFFFFFFFu;
    #pragma unroll
    for (int e = 0; e < 24; ++e) {
        const uint32_t k = key[e];
        if (k > k0 && k < m1) m1 = k;
        if (k > k2 && k < m3) m3 = k;
    }
    {
        uint32_t a = m1, c = m3;
        #pragma unroll
        for (int off = 32; off; off >>= 1) {
            const uint32_t ua = __shfl_down(a, off), uc = __shfl_down(c, off);
            a = (ua < a) ? ua : a; c = (uc < c) ? uc : c;
        }
        if (lane == 0) { umin[wv] = a; umin[8 + wv] = c; }
    }
    __syncthreads();
    uint32_t m1r = 0xFFFFFFFFu, m3r = 0xFFFFFFFFu;
    for (int k = 0; k < 8; ++k) {
        m1r = (umin[k] < m1r) ? umin[k] : m1r;
        m3r = (umin[8 + k] < m3r) ? umin[8 + k] : m3r;
    }
    const uint32_t k1 = dup1 ? k0 : m1r;
    const uint32_t k3 = dup3 ? k2 : m3r;

    // Linear-interpolated quantiles
    const double vl0 = (double)key2f(k0), vl1 = (double)key2f(k1);
    const double vh0 = (double)key2f(k2), vh1 = (double)key2f(k3);
    const double fr_lo = 0.15 * (NRES - 1) - (double)RANK_LO;   // ~0.05
    const double fr_hi = 0.85 * (NRES - 1) - (double)RANK_HI;   // ~0.95
    const float q_lo = (float)(vl0 + fr_lo * (vl1 - vl0));
    const float q_hi = (float)(vh0 + fr_hi * (vh1 - vh0));

    // Pass B: counts + sums under both predicates
    int cq = 0, cs = 0;
    double sq = 0.0, ss = 0.0;
    #pragma unroll
    for (int e = 0; e < 24; ++e) {
        const float f = key2f(key[e]);
        const bool mq = (f < q_lo) || (f > q_hi);
        const bool ms = fabs((double)f - mu) > sd;
        cq += mq; cs += ms;
        if (mq) sq += f;
        if (ms) ss += f;
    }
    {
        double a = sq, c = ss;
        int ai = cq, ci = cs;
        #pragma unroll
        for (int off = 32; off; off >>= 1) {
            a += __shfl_down(a, off); c += __shfl_down(c, off);
            ai += __shfl_down(ai, off); ci += __shfl_down(ci, off);
        }
        if (lane == 0) { dred[wv] = a; dred[8 + wv] = c; ired[wv] = ai; ired[8 + wv] = ci; }
    }
    __syncthreads();
    double sq_t = 0.0, ss_t = 0.0;
    int cq_t = 0, cs_t = 0;
    for (int k = 0; k < 8; ++k) {
        sq_t += dred[k]; ss_t += dred[8 + k];
        cq_t += ired[k]; cs_t += ired[8 + k];
    }

    int mode;                 // 0 = quantile mask, 1 = simple, 2 = all
    double cnt_sel, sum_sel;
    if (cq_t > 0)      { mode = 0; cnt_sel = cq_t; sum_sel = sq_t; }
    else if (cs_t > 0) { mode = 1; cnt_sel = cs_t; sum_sel = ss_t; }
    else               { mode = 2; cnt_sel = NRES; sum_sel = S; }
    const double mean_w = sum_sel / cnt_sel;
    __syncthreads();          // dred reads done before pass C reuses it

    // Pass C: masked unbiased variance
    double acc = 0.0;
    #pragma unroll
    for (int e = 0; e < 24; ++e) {
        const float f = key2f(key[e]);
        bool w;
        if (mode == 0)      w = (f < q_lo) || (f > q_hi);
        else if (mode == 1) w = fabs((double)f - mu) > sd;
        else                w = true;
        if (w) { const double d = (double)f - mean_w; acc += d * d; }
    }
    {
        double a = acc;
        #pragma unroll
        for (int off = 32; off; off >>= 1) a += __shfl_down(a, off);
        if (lane == 0) dred[wv] = a;
    }
    __syncthreads();
    double acc_t = 0.0;
    for (int k = 0; k < 8; ++k) acc_t += dred[k];
    if (tid == 0) sig[pair] = (float)sqrt(acc_t / (cnt_sel - 1.0));
}

// ---------------------------------------------------------------------------
// Kernel 3: out = mean_b max(sig[2b], sig[2b+1])
// ---------------------------------------------------------------------------
__global__ void final_kernel(const float* __restrict__ sig, float* __restrict__ out) {
    const int lane = threadIdx.x;
    float m = 0.f;
    if (lane < NB) m = fmaxf(sig[2 * lane], sig[2 * lane + 1]);
    #pragma unroll
    for (int off = 8; off; off >>= 1) m += __shfl_down(m, off);
    if (lane == 0) out[0] = m / (float)NB;
}

extern "C" void kernel_launch(void* const* d_in, const int* in_sizes, int n_in,
                              void* d_out, int out_size, void* d_ws, size_t ws_size,
                              hipStream_t stream) {
    const float* x = (const float*)d_in[0];
    const float* y = (const float*)d_in[1];
    ull* part = (ull*)d_ws;                                    // 32*8*4096*8 = 8 MB
    float* sig = (float*)((char*)d_ws + (size_t)NPAIR * NTCH * NPTS * 8);
    dim3 g1(NPTS / 1024, NTCH, NPAIR);                         // (4, 8, 32)
    nn_kernel<<<g1, 256, 0, stream>>>(x, y, part);
    sigma_kernel<<<NPAIR, STH, 0, stream>>>(x, y, part, sig);
    final_kernel<<<1, 64, 0, stream>>>(sig, (float*)d_out);
}